// Round 6
// baseline (1606.948 us; speedup 1.0000x reference)
//
#include <hip/hip_runtime.h>
#include <hip/hip_bf16.h>
#include <cstdint>

// Problem constants (fixed shapes from the reference)
#define NB 64
#define LQ 256
#define LD 512
#define HD 768
#define QD_ELEMS (NB * LQ)          // 16384
#define DD_ELEMS (NB * LD)          // 32768
#define CELEMS   (LQ * LD)          // 131072 per batch
#define CTOTAL   ((size_t)NB * CELEMS)  // 8388608

static __device__ __forceinline__ float bflo(unsigned int w) {
    return __uint_as_float(w << 16);
}
static __device__ __forceinline__ float bfhi(unsigned int w) {
    return __uint_as_float(w & 0xffff0000u);
}

// ---------------------------------------------------------------------------
// Kernel: per-row inverse L2 norm (one wave per row of HD=768)
// ---------------------------------------------------------------------------
__global__ __launch_bounds__(256) void rownorm_kernel(const float* __restrict__ x,
                                                      float* __restrict__ inv,
                                                      int rows) {
    int row = blockIdx.x * 4 + (threadIdx.x >> 6);
    int lane = threadIdx.x & 63;
    if (row >= rows) return;
    const float* p = x + (size_t)row * HD;
    float s = 0.f;
#pragma unroll
    for (int i = 0; i < HD / 64; ++i) {
        float v = p[lane + i * 64];
        s += v * v;
    }
#pragma unroll
    for (int off = 32; off; off >>= 1) s += __shfl_down(s, off);
    if (lane == 0) inv[row] = 1.0f / fmaxf(sqrtf(s), 1e-12f);
}

// ---------------------------------------------------------------------------
// Kernel: mask -> distribution (dist = mask / sum(mask)), one block per batch
// ---------------------------------------------------------------------------
__global__ __launch_bounds__(256) void mass_kernel(const float* __restrict__ mask,
                                                   float* __restrict__ dist,
                                                   int L) {
    int b = blockIdx.x;
    int tid = threadIdx.x;
    const float* m = mask + (size_t)b * L;
    float s = 0.f;
    for (int i = tid; i < L; i += 256) s += m[i];
    __shared__ float red[256];
    red[tid] = s;
    __syncthreads();
    for (int st = 128; st; st >>= 1) {
        if (tid < st) red[tid] += red[tid + st];
        __syncthreads();
    }
    float total = red[0];
    for (int i = tid; i < L; i += 256) dist[(size_t)b * L + i] = m[i] / total;
}

// ---------------------------------------------------------------------------
// Kernel: batched GEMM  C[b,q,d] = 1 - (qe[b,q,:]. de[b,d,:]) * qinv * dinv
// 64x64 tile, 256 threads, 4x4 per thread, f32. Also atomicMax per-batch C max.
// ---------------------------------------------------------------------------
__global__ __launch_bounds__(256) void gemm_c_kernel(const float* __restrict__ qe,
                                                     const float* __restrict__ de,
                                                     const float* __restrict__ qinv,
                                                     const float* __restrict__ dinv,
                                                     float* __restrict__ Cout,
                                                     unsigned int* __restrict__ cmax) {
    const int b = blockIdx.z;
    const int m0 = blockIdx.y * 64;
    const int n0 = blockIdx.x * 64;
    const float* A = qe + (size_t)b * LQ * HD;
    const float* Bp = de + (size_t)b * LD * HD;

    __shared__ float As[16][64];
    __shared__ float Bs[16][64];

    float acc[4][4] = {};
    const int tid = threadIdx.x;
    const int tm = tid >> 4, tn = tid & 15;

    for (int k0 = 0; k0 < HD; k0 += 16) {
#pragma unroll
        for (int i = 0; i < 4; ++i) {
            int idx = tid + i * 256;
            int r = idx >> 4, c = idx & 15;
            As[c][r] = A[(size_t)(m0 + r) * HD + k0 + c];
            Bs[c][r] = Bp[(size_t)(n0 + r) * HD + k0 + c];
        }
        __syncthreads();
#pragma unroll
        for (int k = 0; k < 16; ++k) {
            float av[4], bv[4];
#pragma unroll
            for (int i = 0; i < 4; ++i) av[i] = As[k][tm * 4 + i];
#pragma unroll
            for (int j = 0; j < 4; ++j) bv[j] = Bs[k][tn * 4 + j];
#pragma unroll
            for (int i = 0; i < 4; ++i)
#pragma unroll
                for (int j = 0; j < 4; ++j) acc[i][j] += av[i] * bv[j];
        }
        __syncthreads();
    }

    float qi[4], di[4];
#pragma unroll
    for (int i = 0; i < 4; ++i) qi[i] = qinv[(size_t)b * LQ + m0 + tm * 4 + i];
#pragma unroll
    for (int j = 0; j < 4; ++j) di[j] = dinv[(size_t)b * LD + n0 + tn * 4 + j];

    float lmax = -1e30f;
    float* Cb = Cout + (size_t)b * CELEMS;
#pragma unroll
    for (int i = 0; i < 4; ++i) {
        float4 cv;
        float* cp = (float*)&cv;
#pragma unroll
        for (int j = 0; j < 4; ++j) {
            float c = 1.0f - acc[i][j] * qi[i] * di[j];
            cp[j] = c;
            lmax = fmaxf(lmax, c);
        }
        *reinterpret_cast<float4*>(Cb + (size_t)(m0 + tm * 4 + i) * LD + n0 + tn * 4) = cv;
    }

    __shared__ float red[256];
    red[tid] = lmax;
    __syncthreads();
    for (int st = 128; st; st >>= 1) {
        if (tid < st) red[tid] = fmaxf(red[tid], red[tid + st]);
        __syncthreads();
    }
    if (tid == 0) atomicMax(cmax + b, __float_as_uint(red[0]));
}

// ---------------------------------------------------------------------------
// Kernel: K = exp(-C / cmax) stored bf16 (REG = 1)
// ---------------------------------------------------------------------------
__global__ __launch_bounds__(256) void expk_kernel(const float4* __restrict__ C4,
                                                   const unsigned int* __restrict__ cmax,
                                                   ushort4* __restrict__ K4) {
    size_t t = (size_t)blockIdx.x * 256 + threadIdx.x;  // 2097152 total
    int b = (int)(t >> 15);  // (t*4) >> 17
    float inv = -1.0f / __uint_as_float(cmax[b]);
    float4 c = C4[t];
    __hip_bfloat16 h0 = __float2bfloat16(expf(c.x * inv));
    __hip_bfloat16 h1 = __float2bfloat16(expf(c.y * inv));
    __hip_bfloat16 h2 = __float2bfloat16(expf(c.z * inv));
    __hip_bfloat16 h3 = __float2bfloat16(expf(c.w * inv));
    ushort4 o;
    o.x = *reinterpret_cast<unsigned short*>(&h0);
    o.y = *reinterpret_cast<unsigned short*>(&h1);
    o.z = *reinterpret_cast<unsigned short*>(&h2);
    o.w = *reinterpret_cast<unsigned short*>(&h3);
    K4[t] = o;
}

// ---------------------------------------------------------------------------
// Kernel: persistent Sinkhorn — one workgroup per batch, nit iterations.
// K (256 KB/batch, packed bf16) lives ENTIRELY in the register file:
// 16 waves; wave w holds rows [16w,16w+16), lane holds 8 packed columns.
// All per-thread state is named SSA variables — nothing can go to scratch
// UNLESS the backend under-budgets VGPRs. Rounds 2-4 showed the backend
// targets 8 waves/SIMD (64 VGPRs) because 2 blocks/CU *could* fit; the
// 64-block grid on 256 CUs never does that. Pin reality with
// amdgpu_waves_per_eu(4,4) (=> 128-VGPR budget) + LDS pad past 80 KB so
// the LDS-derived occupancy also says 1 block/CU.
// ---------------------------------------------------------------------------
#define ROWS16(OP) OP(0) OP(1) OP(2) OP(3) OP(4) OP(5) OP(6) OP(7) \
                   OP(8) OP(9) OP(10) OP(11) OP(12) OP(13) OP(14) OP(15)

__global__ __launch_bounds__(1024) __attribute__((amdgpu_waves_per_eu(4, 4)))
void sinkhorn_kernel(
        const unsigned short* __restrict__ Kmat,
        const float* __restrict__ qdist,
        const float* __restrict__ ddist,
        const int* __restrict__ nitp,
        float* __restrict__ uout,
        float* __restrict__ vout) {
    const int b = blockIdx.x;
    const int tid = threadIdx.x;
    const int wv = tid >> 6;       // wave 0..15
    const int lane = tid & 63;
    const int d8 = lane << 3;      // column base (0..504)
    const int qbase = wv << 4;     // row base (0..240)

    __shared__ float part[16][LD];  // 32 KB
    __shared__ float vs[LD];
    __shared__ float dd[LD];
    __shared__ float qdl[LQ];
    __shared__ float lds_pad[12288];  // pad total LDS past 81920 B -> 1 block/CU

    const int nit = *nitp;
    if (nit == -12345) lds_pad[tid] = 0.f;  // keep pad alive (never true)

    if (tid < LQ) qdl[tid] = qdist[(size_t)b * LQ + tid];
    if (tid < LD) dd[tid] = ddist[(size_t)b * LD + tid];

    // Load this wave's K slab into named registers: 16 rows x 8 cols (bf16x2).
    const unsigned short* wrow = Kmat + (size_t)b * CELEMS + (size_t)qbase * LD + d8;
#define DECL_K(i) uint4 kk##i = *reinterpret_cast<const uint4*>(wrow + i * LD);
    ROWS16(DECL_K)
#undef DECL_K
#define DECL_U(i) float uu##i = 1.0f;
    ROWS16(DECL_U)
#undef DECL_U

    __syncthreads();

    for (int it = 0; it < nit; ++it) {
        // ---- v-step partials: part[wv][d] = sum_k K[qbase+k][d] * u[k]
        float a0 = 0.f, a1 = 0.f, a2 = 0.f, a3 = 0.f;
        float a4 = 0.f, a5 = 0.f, a6 = 0.f, a7 = 0.f;
#define VSTEP(i) \
        a0 = fmaf(bflo(kk##i.x), uu##i, a0); \
        a1 = fmaf(bfhi(kk##i.x), uu##i, a1); \
        a2 = fmaf(bflo(kk##i.y), uu##i, a2); \
        a3 = fmaf(bfhi(kk##i.y), uu##i, a3); \
        a4 = fmaf(bflo(kk##i.z), uu##i, a4); \
        a5 = fmaf(bfhi(kk##i.z), uu##i, a5); \
        a6 = fmaf(bflo(kk##i.w), uu##i, a6); \
        a7 = fmaf(bfhi(kk##i.w), uu##i, a7);
        ROWS16(VSTEP)
#undef VSTEP
        *reinterpret_cast<float4*>(&part[wv][d8])     = make_float4(a0, a1, a2, a3);
        *reinterpret_cast<float4*>(&part[wv][d8 + 4]) = make_float4(a4, a5, a6, a7);
        __syncthreads();

        // ---- cross-wave reduce + v = dd / colsum
        if (tid < LD) {
            float s = part[0][tid];
#pragma unroll
            for (int w = 1; w < 16; ++w) s += part[w][tid];
            vs[tid] = dd[tid] * __builtin_amdgcn_rcpf(s);
        }
        __syncthreads();

        // ---- u-step: u[k] = qd / sum_d K[row][d] * v[d]
        float4 vlo = *reinterpret_cast<const float4*>(&vs[d8]);
        float4 vhi = *reinterpret_cast<const float4*>(&vs[d8 + 4]);
#define USTEP(i) { \
        float r = bflo(kk##i.x) * vlo.x; \
        r = fmaf(bfhi(kk##i.x), vlo.y, r); \
        r = fmaf(bflo(kk##i.y), vlo.z, r); \
        r = fmaf(bfhi(kk##i.y), vlo.w, r); \
        r = fmaf(bflo(kk##i.z), vhi.x, r); \
        r = fmaf(bfhi(kk##i.z), vhi.y, r); \
        r = fmaf(bflo(kk##i.w), vhi.z, r); \
        r = fmaf(bfhi(kk##i.w), vhi.w, r); \
        r += __shfl_xor(r, 32); \
        r += __shfl_xor(r, 16); \
        r += __shfl_xor(r, 8); \
        r += __shfl_xor(r, 4); \
        r += __shfl_xor(r, 2); \
        r += __shfl_xor(r, 1); \
        uu##i = qdl[qbase + i] * __builtin_amdgcn_rcpf(r); }
        ROWS16(USTEP)
#undef USTEP
        // No 3rd barrier: next part-write is fenced from this iter's
        // part-reads by the post-reduce barrier; next iter's vs-write is
        // fenced from this iter's vs-reads by the pre-reduce barrier.
    }

    if (tid < LD) vout[(size_t)b * LD + tid] = (nit > 0) ? vs[tid] : 0.0f;
    if (lane == 0) {
        float* up = uout + (size_t)b * LQ + qbase;
#define WRITE_U(i) up[i] = uu##i;
        ROWS16(WRITE_U)
#undef WRITE_U
    }
}

// ---------------------------------------------------------------------------
// Kernel: T = u*K*v, partial distances = sum(C*T) per (batch, chunk)
// grid (4, NB), 256 threads
// ---------------------------------------------------------------------------
__global__ __launch_bounds__(256) void tdist_kernel(const float* __restrict__ C,
                                                    const __hip_bfloat16* __restrict__ K,
                                                    const float* __restrict__ u,
                                                    const float* __restrict__ v,
                                                    float* __restrict__ T,
                                                    float* __restrict__ part) {
    const int b = blockIdx.y;
    const int ch = blockIdx.x;
    const int tid = threadIdx.x;
    __shared__ float us[LQ], vs[LD];
    us[tid] = u[(size_t)b * LQ + tid];
    vs[tid] = v[(size_t)b * LD + tid];
    vs[tid + 256] = v[(size_t)b * LD + 256 + tid];
    __syncthreads();

    const __hip_bfloat16* Kb = K + (size_t)b * CELEMS;
    const float* Cb = C + (size_t)b * CELEMS;
    float* Tb = T + (size_t)b * CELEMS;

    float local = 0.f;
    const int chunk = CELEMS / 4;  // 32768
    for (int i = tid; i < chunk; i += 256) {
        int e = ch * chunk + i;
        int q = e >> 9;
        int dj = e & (LD - 1);
        float kk = __bfloat162float(Kb[e]);
        float t = us[q] * kk * vs[dj];
        Tb[e] = t;
        local += Cb[e] * t;
    }

    __shared__ float red[256];
    red[tid] = local;
    __syncthreads();
    for (int st = 128; st; st >>= 1) {
        if (tid < st) red[tid] += red[tid + st];
        __syncthreads();
    }
    if (tid == 0) part[b * 4 + ch] = red[0];
}

__global__ void final_dist_kernel(const float* __restrict__ part, float* __restrict__ dist) {
    int b = threadIdx.x;
    if (b < NB) dist[b] = part[b * 4] + part[b * 4 + 1] + part[b * 4 + 2] + part[b * 4 + 3];
}

// ---------------------------------------------------------------------------
extern "C" void kernel_launch(void* const* d_in, const int* in_sizes, int n_in,
                              void* d_out, int out_size, void* d_ws, size_t ws_size,
                              hipStream_t stream) {
    const float* qe = (const float*)d_in[0];
    const float* qmask = (const float*)d_in[1];
    const float* de = (const float*)d_in[2];
    const float* dmask = (const float*)d_in[3];
    const int* nit = (const int*)d_in[4];

    float* out = (float*)d_out;
    float* dist = out;
    float* Cout = out + 64;
    float* Tout = out + 64 + CTOTAL;

    // Workspace layout
    char* ws = (char*)d_ws;
    size_t off = 0;
    __hip_bfloat16* Kw = (__hip_bfloat16*)(ws + off); off += CTOTAL * 2;          // 16 MB
    float* qinv  = (float*)(ws + off); off += (size_t)QD_ELEMS * 4;
    float* dinv  = (float*)(ws + off); off += (size_t)DD_ELEMS * 4;
    float* qdist = (float*)(ws + off); off += (size_t)QD_ELEMS * 4;
    float* ddist = (float*)(ws + off); off += (size_t)DD_ELEMS * 4;
    unsigned int* cmax = (unsigned int*)(ws + off); off += NB * 4;
    float* uvec  = (float*)(ws + off); off += (size_t)QD_ELEMS * 4;
    float* vvec  = (float*)(ws + off); off += (size_t)DD_ELEMS * 4;
    float* part  = (float*)(ws + off); off += NB * 4 * 4;

    hipMemsetAsync(cmax, 0, NB * 4, stream);

    rownorm_kernel<<<QD_ELEMS / 4, 256, 0, stream>>>(qe, qinv, QD_ELEMS);
    rownorm_kernel<<<DD_ELEMS / 4, 256, 0, stream>>>(de, dinv, DD_ELEMS);

    mass_kernel<<<NB, 256, 0, stream>>>(qmask, qdist, LQ);
    mass_kernel<<<NB, 256, 0, stream>>>(dmask, ddist, LD);

    dim3 ggrid(LD / 64, LQ / 64, NB);
    gemm_c_kernel<<<ggrid, 256, 0, stream>>>(qe, de, qinv, dinv, Cout, cmax);

    expk_kernel<<<(CTOTAL / 4) / 256, 256, 0, stream>>>((const float4*)Cout, cmax, (ushort4*)Kw);

    sinkhorn_kernel<<<NB, 1024, 0, stream>>>((const unsigned short*)Kw, qdist, ddist, nit, uvec, vvec);

    dim3 tgrid(4, NB);
    tdist_kernel<<<tgrid, 256, 0, stream>>>(Cout, Kw, uvec, vvec, Tout, part);

    final_dist_kernel<<<1, 64, 0, stream>>>(part, dist);
}

// Round 8
// 1097.279 us; speedup vs baseline: 1.4645x; 1.4645x over previous
//
#include <hip/hip_runtime.h>
#include <hip/hip_bf16.h>
#include <cstdint>

// Problem constants (fixed shapes from the reference)
#define NB 64
#define LQ 256
#define LD 512
#define HD 768
#define QD_ELEMS (NB * LQ)          // 16384
#define DD_ELEMS (NB * LD)          // 32768
#define CELEMS   (LQ * LD)          // 131072 per batch
#define CTOTAL   ((size_t)NB * CELEMS)  // 8388608

static __device__ __forceinline__ float bflo(unsigned int w) {
    return __uint_as_float(w << 16);
}
static __device__ __forceinline__ float bfhi(unsigned int w) {
    return __uint_as_float(w & 0xffff0000u);
}

// ---------------------------------------------------------------------------
// Kernel: per-row inverse L2 norm (one wave per row of HD=768)
// ---------------------------------------------------------------------------
__global__ __launch_bounds__(256) void rownorm_kernel(const float* __restrict__ x,
                                                      float* __restrict__ inv,
                                                      int rows) {
    int row = blockIdx.x * 4 + (threadIdx.x >> 6);
    int lane = threadIdx.x & 63;
    if (row >= rows) return;
    const float* p = x + (size_t)row * HD;
    float s = 0.f;
#pragma unroll
    for (int i = 0; i < HD / 64; ++i) {
        float v = p[lane + i * 64];
        s += v * v;
    }
#pragma unroll
    for (int off = 32; off; off >>= 1) s += __shfl_down(s, off);
    if (lane == 0) inv[row] = 1.0f / fmaxf(sqrtf(s), 1e-12f);
}

// ---------------------------------------------------------------------------
// Kernel: mask -> distribution (dist = mask / sum(mask)), one block per batch
// ---------------------------------------------------------------------------
__global__ __launch_bounds__(256) void mass_kernel(const float* __restrict__ mask,
                                                   float* __restrict__ dist,
                                                   int L) {
    int b = blockIdx.x;
    int tid = threadIdx.x;
    const float* m = mask + (size_t)b * L;
    float s = 0.f;
    for (int i = tid; i < L; i += 256) s += m[i];
    __shared__ float red[256];
    red[tid] = s;
    __syncthreads();
    for (int st = 128; st; st >>= 1) {
        if (tid < st) red[tid] += red[tid + st];
        __syncthreads();
    }
    float total = red[0];
    for (int i = tid; i < L; i += 256) dist[(size_t)b * L + i] = m[i] / total;
}

// ---------------------------------------------------------------------------
// Kernel: batched GEMM  C[b,q,d] = 1 - (qe[b,q,:]. de[b,d,:]) * qinv * dinv
// 64x64 tile, 256 threads, 4x4 per thread, f32. Also atomicMax per-batch C max.
// ---------------------------------------------------------------------------
__global__ __launch_bounds__(256) void gemm_c_kernel(const float* __restrict__ qe,
                                                     const float* __restrict__ de,
                                                     const float* __restrict__ qinv,
                                                     const float* __restrict__ dinv,
                                                     float* __restrict__ Cout,
                                                     unsigned int* __restrict__ cmax) {
    const int b = blockIdx.z;
    const int m0 = blockIdx.y * 64;
    const int n0 = blockIdx.x * 64;
    const float* A = qe + (size_t)b * LQ * HD;
    const float* Bp = de + (size_t)b * LD * HD;

    __shared__ float As[16][64];
    __shared__ float Bs[16][64];

    float acc[4][4] = {};
    const int tid = threadIdx.x;
    const int tm = tid >> 4, tn = tid & 15;

    for (int k0 = 0; k0 < HD; k0 += 16) {
#pragma unroll
        for (int i = 0; i < 4; ++i) {
            int idx = tid + i * 256;
            int r = idx >> 4, c = idx & 15;
            As[c][r] = A[(size_t)(m0 + r) * HD + k0 + c];
            Bs[c][r] = Bp[(size_t)(n0 + r) * HD + k0 + c];
        }
        __syncthreads();
#pragma unroll
        for (int k = 0; k < 16; ++k) {
            float av[4], bv[4];
#pragma unroll
            for (int i = 0; i < 4; ++i) av[i] = As[k][tm * 4 + i];
#pragma unroll
            for (int j = 0; j < 4; ++j) bv[j] = Bs[k][tn * 4 + j];
#pragma unroll
            for (int i = 0; i < 4; ++i)
#pragma unroll
                for (int j = 0; j < 4; ++j) acc[i][j] += av[i] * bv[j];
        }
        __syncthreads();
    }

    float qi[4], di[4];
#pragma unroll
    for (int i = 0; i < 4; ++i) qi[i] = qinv[(size_t)b * LQ + m0 + tm * 4 + i];
#pragma unroll
    for (int j = 0; j < 4; ++j) di[j] = dinv[(size_t)b * LD + n0 + tn * 4 + j];

    float lmax = -1e30f;
    float* Cb = Cout + (size_t)b * CELEMS;
#pragma unroll
    for (int i = 0; i < 4; ++i) {
        float4 cv;
        float* cp = (float*)&cv;
#pragma unroll
        for (int j = 0; j < 4; ++j) {
            float c = 1.0f - acc[i][j] * qi[i] * di[j];
            cp[j] = c;
            lmax = fmaxf(lmax, c);
        }
        *reinterpret_cast<float4*>(Cb + (size_t)(m0 + tm * 4 + i) * LD + n0 + tn * 4) = cv;
    }

    __shared__ float red[256];
    red[tid] = lmax;
    __syncthreads();
    for (int st = 128; st; st >>= 1) {
        if (tid < st) red[tid] = fmaxf(red[tid], red[tid + st]);
        __syncthreads();
    }
    if (tid == 0) atomicMax(cmax + b, __float_as_uint(red[0]));
}

// ---------------------------------------------------------------------------
// Kernel: K = exp(-C / cmax) stored bf16 (REG = 1)
// ---------------------------------------------------------------------------
__global__ __launch_bounds__(256) void expk_kernel(const float4* __restrict__ C4,
                                                   const unsigned int* __restrict__ cmax,
                                                   ushort4* __restrict__ K4) {
    size_t t = (size_t)blockIdx.x * 256 + threadIdx.x;  // 2097152 total
    int b = (int)(t >> 15);  // (t*4) >> 17
    float inv = -1.0f / __uint_as_float(cmax[b]);
    float4 c = C4[t];
    __hip_bfloat16 h0 = __float2bfloat16(expf(c.x * inv));
    __hip_bfloat16 h1 = __float2bfloat16(expf(c.y * inv));
    __hip_bfloat16 h2 = __float2bfloat16(expf(c.z * inv));
    __hip_bfloat16 h3 = __float2bfloat16(expf(c.w * inv));
    ushort4 o;
    o.x = *reinterpret_cast<unsigned short*>(&h0);
    o.y = *reinterpret_cast<unsigned short*>(&h1);
    o.z = *reinterpret_cast<unsigned short*>(&h2);
    o.w = *reinterpret_cast<unsigned short*>(&h3);
    K4[t] = o;
}

// ---------------------------------------------------------------------------
// Kernel: persistent Sinkhorn — one workgroup per batch, nit iterations.
// Design under the 64-VGPR budget the backend picks:
//   - wave w owns rows [16w,16w+16): rows 0-7 in REGISTERS (32 VGPRs),
//     rows 8-15 in LDS (16 waves x 8 KB = 128 KB, real & un-DCE-able,
//     which also forces 1 block/CU in the backend occupancy calc).
//   - u lives in a tiny LDS array (broadcast b32 reads, 1 ds_write/iter)
//     so peak live VGPRs ~55-60 -> no spill even at a 64-reg budget.
//   - v-reduction: deterministic two-phase (waves 0-7 store partials,
//     waves 8-15 RMW-add theirs, then 8-way column sum). 3 barriers/iter.
// All LDS patterns conflict-free (contiguous 16 B/lane; broadcasts).
// ---------------------------------------------------------------------------
#define ROWS8L(OP) OP(0) OP(1) OP(2) OP(3) OP(4) OP(5) OP(6) OP(7)
#define ROWS8H(OP) OP(8) OP(9) OP(10) OP(11) OP(12) OP(13) OP(14) OP(15)

__global__ __launch_bounds__(1024) __attribute__((amdgpu_waves_per_eu(4, 4)))
void sinkhorn_kernel(
        const unsigned short* __restrict__ Kmat,
        const float* __restrict__ qdist,
        const float* __restrict__ ddist,
        const int* __restrict__ nitp,
        float* __restrict__ uout,
        float* __restrict__ vout) {
    const int b = blockIdx.x;
    const int tid = threadIdx.x;
    const int wv = tid >> 6;       // wave 0..15
    const int lane = tid & 63;
    const int d8 = lane << 3;      // column base (0..504)
    const int qbase = wv << 4;     // row base (0..240)

    __shared__ unsigned short Klds[16][8][512];  // 128 KB: rows 8-15 per wave
    __shared__ float part8[8][512];              // 16 KB partials
    __shared__ float vs[LD];
    __shared__ float dd[LD];
    __shared__ float qdl[LQ];
    __shared__ float ulds[16][16];               // u[wave][row]

    if (tid < LQ) qdl[tid] = qdist[(size_t)b * LQ + tid];
    if (tid < LD) dd[tid] = ddist[(size_t)b * LD + tid];
    if (tid < LQ) ulds[tid >> 4][tid & 15] = 1.0f;

    // Stage this wave's K slab: rows 0-7 -> registers, rows 8-15 -> LDS.
    const unsigned short* wrow = Kmat + (size_t)b * CELEMS + (size_t)qbase * LD + d8;
#define DECL_K(i) uint4 kk##i = *reinterpret_cast<const uint4*>(wrow + i * LD);
    ROWS8L(DECL_K)
#undef DECL_K
#pragma unroll
    for (int k = 0; k < 8; ++k)
        *reinterpret_cast<uint4*>(&Klds[wv][k][d8]) =
            *reinterpret_cast<const uint4*>(wrow + (size_t)(8 + k) * LD);

    __syncthreads();
    const int nit = *nitp;

    for (int it = 0; it < nit; ++it) {
        // ---- v-step partials: acc[d] = sum_{k=0..15} K[qbase+k][d] * u[k]
        float a0 = 0.f, a1 = 0.f, a2 = 0.f, a3 = 0.f;
        float a4 = 0.f, a5 = 0.f, a6 = 0.f, a7 = 0.f;
#define VSTEP_R(i) { const float uk = ulds[wv][i]; \
        a0 = fmaf(bflo(kk##i.x), uk, a0); \
        a1 = fmaf(bfhi(kk##i.x), uk, a1); \
        a2 = fmaf(bflo(kk##i.y), uk, a2); \
        a3 = fmaf(bfhi(kk##i.y), uk, a3); \
        a4 = fmaf(bflo(kk##i.z), uk, a4); \
        a5 = fmaf(bfhi(kk##i.z), uk, a5); \
        a6 = fmaf(bflo(kk##i.w), uk, a6); \
        a7 = fmaf(bfhi(kk##i.w), uk, a7); }
        ROWS8L(VSTEP_R)
#undef VSTEP_R
#define VSTEP_L(i) { const float uk = ulds[wv][i]; \
        const uint4 kw = *reinterpret_cast<const uint4*>(&Klds[wv][(i) - 8][d8]); \
        a0 = fmaf(bflo(kw.x), uk, a0); \
        a1 = fmaf(bfhi(kw.x), uk, a1); \
        a2 = fmaf(bflo(kw.y), uk, a2); \
        a3 = fmaf(bfhi(kw.y), uk, a3); \
        a4 = fmaf(bflo(kw.z), uk, a4); \
        a5 = fmaf(bfhi(kw.z), uk, a5); \
        a6 = fmaf(bflo(kw.w), uk, a6); \
        a7 = fmaf(bfhi(kw.w), uk, a7); }
        ROWS8H(VSTEP_L)
#undef VSTEP_L

        // Phase A: waves 0-7 store partials.
        if (wv < 8) {
            *reinterpret_cast<float4*>(&part8[wv][d8])     = make_float4(a0, a1, a2, a3);
            *reinterpret_cast<float4*>(&part8[wv][d8 + 4]) = make_float4(a4, a5, a6, a7);
        }
        __syncthreads();
        // Phase B: waves 8-15 add theirs (1:1 mapping, no races).
        if (wv >= 8) {
            float4 p0 = *reinterpret_cast<const float4*>(&part8[wv - 8][d8]);
            float4 p1 = *reinterpret_cast<const float4*>(&part8[wv - 8][d8 + 4]);
            p0.x += a0; p0.y += a1; p0.z += a2; p0.w += a3;
            p1.x += a4; p1.y += a5; p1.z += a6; p1.w += a7;
            *reinterpret_cast<float4*>(&part8[wv - 8][d8])     = p0;
            *reinterpret_cast<float4*>(&part8[wv - 8][d8 + 4]) = p1;
        }
        __syncthreads();
        // Column sum + v = dd / colsum
        if (tid < LD) {
            float s = part8[0][tid] + part8[1][tid] + part8[2][tid] + part8[3][tid]
                    + part8[4][tid] + part8[5][tid] + part8[6][tid] + part8[7][tid];
            vs[tid] = dd[tid] * __builtin_amdgcn_rcpf(s);
        }
        __syncthreads();

        // ---- u-step: u[k] = qd[k] / sum_d K[row][d] * v[d]
        const float4 vlo = *reinterpret_cast<const float4*>(&vs[d8]);
        const float4 vhi = *reinterpret_cast<const float4*>(&vs[d8 + 4]);
        float myu = 0.f;
#define UDOT(KW, i) { \
        float r = bflo(KW.x) * vlo.x; \
        r = fmaf(bfhi(KW.x), vlo.y, r); \
        r = fmaf(bflo(KW.y), vlo.z, r); \
        r = fmaf(bfhi(KW.y), vlo.w, r); \
        r = fmaf(bflo(KW.z), vhi.x, r); \
        r = fmaf(bfhi(KW.z), vhi.y, r); \
        r = fmaf(bflo(KW.w), vhi.z, r); \
        r = fmaf(bfhi(KW.w), vhi.w, r); \
        r += __shfl_xor(r, 32); \
        r += __shfl_xor(r, 16); \
        r += __shfl_xor(r, 8); \
        r += __shfl_xor(r, 4); \
        r += __shfl_xor(r, 2); \
        r += __shfl_xor(r, 1); \
        const float uv = qdl[qbase + (i)] * __builtin_amdgcn_rcpf(r); \
        myu = (lane == (i)) ? uv : myu; }
#define USTEP_R(i) UDOT(kk##i, i)
        ROWS8L(USTEP_R)
#undef USTEP_R
#define USTEP_L(i) { \
        const uint4 kw = *reinterpret_cast<const uint4*>(&Klds[wv][(i) - 8][d8]); \
        UDOT(kw, i) }
        ROWS8H(USTEP_L)
#undef USTEP_L
#undef UDOT
        if (lane < 16) ulds[wv][lane] = myu;
        // ulds[wv] is only read by its own wave inside the loop: intra-wave
        // DS ordering (lgkmcnt) suffices, no extra barrier. part8 next-iter
        // writes are fenced by the post-reduce barrier above.
    }

    __syncthreads();
    if (tid < LD) vout[(size_t)b * LD + tid] = (nit > 0) ? vs[tid] : 0.0f;
    if (tid < LQ) uout[(size_t)b * LQ + tid] = ulds[tid >> 4][tid & 15];
}

// ---------------------------------------------------------------------------
// Kernel: T = u*K*v, partial distances = sum(C*T) per (batch, chunk)
// grid (4, NB), 256 threads
// ---------------------------------------------------------------------------
__global__ __launch_bounds__(256) void tdist_kernel(const float* __restrict__ C,
                                                    const __hip_bfloat16* __restrict__ K,
                                                    const float* __restrict__ u,
                                                    const float* __restrict__ v,
                                                    float* __restrict__ T,
                                                    float* __restrict__ part) {
    const int b = blockIdx.y;
    const int ch = blockIdx.x;
    const int tid = threadIdx.x;
    __shared__ float us[LQ], vs[LD];
    us[tid] = u[(size_t)b * LQ + tid];
    vs[tid] = v[(size_t)b * LD + tid];
    vs[tid + 256] = v[(size_t)b * LD + 256 + tid];
    __syncthreads();

    const __hip_bfloat16* Kb = K + (size_t)b * CELEMS;
    const float* Cb = C + (size_t)b * CELEMS;
    float* Tb = T + (size_t)b * CELEMS;

    float local = 0.f;
    const int chunk = CELEMS / 4;  // 32768
    for (int i = tid; i < chunk; i += 256) {
        int e = ch * chunk + i;
        int q = e >> 9;
        int dj = e & (LD - 1);
        float kk = __bfloat162float(Kb[e]);
        float t = us[q] * kk * vs[dj];
        Tb[e] = t;
        local += Cb[e] * t;
    }

    __shared__ float red[256];
    red[tid] = local;
    __syncthreads();
    for (int st = 128; st; st >>= 1) {
        if (tid < st) red[tid] += red[tid + st];
        __syncthreads();
    }
    if (tid == 0) part[b * 4 + ch] = red[0];
}

__global__ void final_dist_kernel(const float* __restrict__ part, float* __restrict__ dist) {
    int b = threadIdx.x;
    if (b < NB) dist[b] = part[b * 4] + part[b * 4 + 1] + part[b * 4 + 2] + part[b * 4 + 3];
}

// ---------------------------------------------------------------------------
extern "C" void kernel_launch(void* const* d_in, const int* in_sizes, int n_in,
                              void* d_out, int out_size, void* d_ws, size_t ws_size,
                              hipStream_t stream) {
    const float* qe = (const float*)d_in[0];
    const float* qmask = (const float*)d_in[1];
    const float* de = (const float*)d_in[2];
    const float* dmask = (const float*)d_in[3];
    const int* nit = (const int*)d_in[4];

    float* out = (float*)d_out;
    float* dist = out;
    float* Cout = out + 64;
    float* Tout = out + 64 + CTOTAL;

    // Workspace layout
    char* ws = (char*)d_ws;
    size_t off = 0;
    __hip_bfloat16* Kw = (__hip_bfloat16*)(ws + off); off += CTOTAL * 2;          // 16 MB
    float* qinv  = (float*)(ws + off); off += (size_t)QD_ELEMS * 4;
    float* dinv  = (float*)(ws + off); off += (size_t)DD_ELEMS * 4;
    float* qdist = (float*)(ws + off); off += (size_t)QD_ELEMS * 4;
    float* ddist = (float*)(ws + off); off += (size_t)DD_ELEMS * 4;
    unsigned int* cmax = (unsigned int*)(ws + off); off += NB * 4;
    float* uvec  = (float*)(ws + off); off += (size_t)QD_ELEMS * 4;
    float* vvec  = (float*)(ws + off); off += (size_t)DD_ELEMS * 4;
    float* part  = (float*)(ws + off); off += NB * 4 * 4;

    hipMemsetAsync(cmax, 0, NB * 4, stream);

    rownorm_kernel<<<QD_ELEMS / 4, 256, 0, stream>>>(qe, qinv, QD_ELEMS);
    rownorm_kernel<<<DD_ELEMS / 4, 256, 0, stream>>>(de, dinv, DD_ELEMS);

    mass_kernel<<<NB, 256, 0, stream>>>(qmask, qdist, LQ);
    mass_kernel<<<NB, 256, 0, stream>>>(dmask, ddist, LD);

    dim3 ggrid(LD / 64, LQ / 64, NB);
    gemm_c_kernel<<<ggrid, 256, 0, stream>>>(qe, de, qinv, dinv, Cout, cmax);

    expk_kernel<<<(CTOTAL / 4) / 256, 256, 0, stream>>>((const float4*)Cout, cmax, (ushort4*)Kw);

    sinkhorn_kernel<<<NB, 1024, 0, stream>>>((const unsigned short*)Kw, qdist, ddist, nit, uvec, vvec);

    dim3 tgrid(4, NB);
    tdist_kernel<<<tgrid, 256, 0, stream>>>(Cout, Kw, uvec, vvec, Tout, part);

    final_dist_kernel<<<1, 64, 0, stream>>>(part, dist);
}